// Round 5
// baseline (455.239 us; speedup 1.0000x reference)
//
#include <hip/hip_runtime.h>
#include <math.h>

#define BB 8
#define NPTS 80000
#define KK 5
#define FF 20
#define GG 125                 // blocks per batch -> 1000 blocks, 10 tiles each
#define TILE 64
#define NTILES (NPTS / TILE)   // 1250
#define JT (NTILES / GG)       // 10 tiles per block, exact
#define RSUB 8                 // partial sub-rows per (b,k,g) (lanes 0..7 after 3-step reduce)
#define PR 44                  // sub-row stride: 20 s1 + 20 s2 + 1 s0 + pad

// ws layout (floats)
#define WS_A 0                 // A coef [B*K] = 40 (padded to 64)
#define WS_R 64                // packed coef rows [B][F][10]: d[k] at +k, e[k] at +5+k

// ================= coefficient preparation =================
__global__ void prepare_kernel(const float* __restrict__ means, const float* __restrict__ var,
                               const float* __restrict__ pi, float* __restrict__ ws) {
    int t = threadIdx.x;
    if (t < BB * KK) {
        int b = t / KK, k = t % KK;
        float sumlog = 0.f, summ2 = 0.f;
        for (int f = 0; f < FF; ++f) {
            float v = var[t * FF + f];
            float m = means[t * FF + f];
            float ic = 1.f / (v + 1e-6f);
            sumlog += logf(6.283185307179586f * v);
            summ2  += ic * m * m;
            float* R = ws + WS_R + (b * FF + f) * 10;
            R[k]     = ic * m;      // d
            R[5 + k] = -0.5f * ic;  // e
        }
        (ws + WS_A)[t] = logf(pi[t]) - 0.5f * sumlog - 0.5f * summ2;
    }
}

// ================= E-step accumulate: zero LDS, zero barriers =================
template <int KLO, int NK>
__device__ __forceinline__ void estep_acc_wave(const float* __restrict__ dbase,
                                               const float* cf, const float* __restrict__ Ab,
                                               int b, int g, int lane,
                                               float* __restrict__ partials) {
    const float A0 = Ab[0], A1 = Ab[1], A2 = Ab[2], A3 = Ab[3], A4 = Ab[4];
    float s0[NK], s1[NK][FF], s2[NK][FF];
#pragma unroll
    for (int q = 0; q < NK; ++q) {
        s0[q] = 0.f;
#pragma unroll
        for (int f = 0; f < FF; ++f) { s1[q][f] = 0.f; s2[q][f] = 0.f; }
    }

    for (int j = 0; j < JT; ++j) {
        asm volatile("" : "+s"(cf));   // block LICM: coef loads stay in-loop (scalar, L1-hot)
        const int tile = g + j * GG;
        const float4* tp = (const float4*)(dbase + (size_t)tile * TILE * FF);
        float4 x4[5];
#pragma unroll
        for (int i = 0; i < 5; ++i) x4[i] = tp[lane * 5 + i];
        float xv[FF];
#pragma unroll
        for (int i = 0; i < 5; ++i) {
            xv[i * 4 + 0] = x4[i].x; xv[i * 4 + 1] = x4[i].y;
            xv[i * 4 + 2] = x4[i].z; xv[i * 4 + 3] = x4[i].w;
        }
        float z0 = A0, z1 = A1, z2 = A2, z3 = A3, z4 = A4;
#pragma unroll
        for (int f = 0; f < FF; ++f) {
            const float* r = cf + f * 10;
            float x = xv[f];
            z0 = fmaf(x, fmaf(r[5], x, r[0]), z0);
            z1 = fmaf(x, fmaf(r[6], x, r[1]), z1);
            z2 = fmaf(x, fmaf(r[7], x, r[2]), z2);
            z3 = fmaf(x, fmaf(r[8], x, r[3]), z3);
            z4 = fmaf(x, fmaf(r[9], x, r[4]), z4);
        }
        float mx = fmaxf(fmaxf(fmaxf(z0, z1), fmaxf(z2, z3)), z4);
        float e0 = __expf(z0 - mx), e1 = __expf(z1 - mx), e2 = __expf(z2 - mx),
              e3 = __expf(z3 - mx), e4 = __expf(z4 - mx);
        float inv = 1.f / (e0 + e1 + e2 + e3 + e4);
        float ev[5] = {e0, e1, e2, e3, e4};
#pragma unroll
        for (int q = 0; q < NK; ++q) {
            float p = ev[KLO + q] * inv;
            s0[q] += p;
#pragma unroll
            for (int f = 0; f < FF; ++f) {
                float px = p * xv[f];
                s1[q][f] += px;
                s2[q][f] = fmaf(px, xv[f], s2[q][f]);
            }
        }
    }

    // 3-step shuffle reduce -> lanes 0..7 hold 8-way partial sums
#pragma unroll
    for (int off = 32; off >= 8; off >>= 1) {
#pragma unroll
        for (int q = 0; q < NK; ++q) {
            s0[q] += __shfl_down(s0[q], off);
#pragma unroll
            for (int f = 0; f < FF; ++f) {
                s1[q][f] += __shfl_down(s1[q][f], off);
                s2[q][f] += __shfl_down(s2[q][f], off);
            }
        }
    }
    if (lane < RSUB) {
#pragma unroll
        for (int q = 0; q < NK; ++q) {
            float* row = partials + (((size_t)(b * KK + KLO + q) * GG + g) * RSUB + lane) * PR;
#pragma unroll
            for (int f = 0; f < FF; ++f) { row[f] = s1[q][f]; row[FF + f] = s2[q][f]; }
            row[2 * FF] = s0[q];
        }
    }
}

__global__ __launch_bounds__(128) void estep_acc_kernel(const float* __restrict__ data,
                                                        const float* __restrict__ ws,
                                                        float* __restrict__ partials) {
    const int b    = blockIdx.x / GG;
    const int g    = blockIdx.x % GG;
    const int wv   = threadIdx.x >> 6;
    const int lane = threadIdx.x & 63;
    const float* cf    = ws + WS_R + b * FF * 10;
    const float* Ab    = ws + WS_A + b * KK;
    const float* dbase = data + (size_t)b * NPTS * FF;
    if (wv == 0) estep_acc_wave<0, 2>(dbase, cf, Ab, b, g, lane, partials);
    else         estep_acc_wave<2, 3>(dbase, cf, Ab, b, g, lane, partials);
}

// ================= final E-step: write ll & post =================
__global__ __launch_bounds__(128) void estep_write_kernel(const float* __restrict__ data,
                                                          const float* __restrict__ ws,
                                                          float* __restrict__ out_ll,
                                                          float* __restrict__ out_post) {
    const int b    = blockIdx.x / GG;
    const int g    = blockIdx.x % GG;
    const int wv   = threadIdx.x >> 6;
    const int lane = threadIdx.x & 63;
    const float* cf    = ws + WS_R + b * FF * 10;
    const float* Ab    = ws + WS_A + b * KK;
    const float* dbase = data + (size_t)b * NPTS * FF;
    const float A0 = Ab[0], A1 = Ab[1], A2 = Ab[2], A3 = Ab[3], A4 = Ab[4];

    for (int j = 0; j < JT; ++j) {
        asm volatile("" : "+s"(cf));
        const int tile = g + j * GG;
        const float4* tp = (const float4*)(dbase + (size_t)tile * TILE * FF);
        float4 x4[5];
#pragma unroll
        for (int i = 0; i < 5; ++i) x4[i] = tp[lane * 5 + i];
        float xv[FF];
#pragma unroll
        for (int i = 0; i < 5; ++i) {
            xv[i * 4 + 0] = x4[i].x; xv[i * 4 + 1] = x4[i].y;
            xv[i * 4 + 2] = x4[i].z; xv[i * 4 + 3] = x4[i].w;
        }
        float z0 = A0, z1 = A1, z2 = A2, z3 = A3, z4 = A4;
#pragma unroll
        for (int f = 0; f < FF; ++f) {
            const float* r = cf + f * 10;
            float x = xv[f];
            z0 = fmaf(x, fmaf(r[5], x, r[0]), z0);
            z1 = fmaf(x, fmaf(r[6], x, r[1]), z1);
            z2 = fmaf(x, fmaf(r[7], x, r[2]), z2);
            z3 = fmaf(x, fmaf(r[8], x, r[3]), z3);
            z4 = fmaf(x, fmaf(r[9], x, r[4]), z4);
        }
        float mx = fmaxf(fmaxf(fmaxf(z0, z1), fmaxf(z2, z3)), z4);
        float e0 = __expf(z0 - mx), e1 = __expf(z1 - mx), e2 = __expf(z2 - mx),
              e3 = __expf(z3 - mx), e4 = __expf(z4 - mx);
        float inv = 1.f / (e0 + e1 + e2 + e3 + e4);

        size_t o = ((size_t)b * NPTS + (size_t)tile * TILE + lane) * KK;
        if (wv == 0) {
            out_ll[o + 0] = z0; out_ll[o + 1] = z1; out_ll[o + 2] = z2;
            out_ll[o + 3] = z3; out_ll[o + 4] = z4;
        } else {
            out_post[o + 0] = e0 * inv; out_post[o + 1] = e1 * inv; out_post[o + 2] = e2 * inv;
            out_post[o + 3] = e3 * inv; out_post[o + 4] = e4 * inv;
        }
    }
}

// ================= reduce partials + M-step + next coefs =================
__global__ __launch_bounds__(320) void update_kernel(const float* __restrict__ partials,
                                                     float* __restrict__ ws,
                                                     float* __restrict__ om,
                                                     float* __restrict__ ov,
                                                     float* __restrict__ op,
                                                     int write_params) {
    __shared__ float s0s[KK];
    const int b    = blockIdx.x;
    const int tid  = threadIdx.x;
    const int w    = tid >> 6;
    const int lane = tid & 63;
    const int bk   = b * KK + w;

    float a0 = 0.f, a1 = 0.f, a2 = 0.f, a3 = 0.f;
    if (lane < 2 * FF + 1) {
        const float* base = partials + (size_t)bk * GG * RSUB * PR + lane;
        for (int r = 0; r < GG * RSUB; r += 4) {
            a0 += base[(size_t)(r + 0) * PR];
            a1 += base[(size_t)(r + 1) * PR];
            a2 += base[(size_t)(r + 2) * PR];
            a3 += base[(size_t)(r + 3) * PR];
        }
    }
    float sv = (a0 + a1) + (a2 + a3);

    float s0  = __shfl(sv, 2 * FF);
    float den = s0 + 1e-7f;
    float m   = sv / den;                      // lanes 0..19: mean[f]
    float s2f = __shfl(sv, FF + (lane % FF));  // S2[f] for lane f
    float var = (s2f - 2.f * m * sv + m * m * s0) / den + 1e-6f;

    if (write_params && lane < FF) {
        om[bk * FF + lane] = m;
        ov[bk * FF + lane] = var;
    }

    if (lane == 0) s0s[w] = s0;
    __syncthreads();
    float tot = s0s[0] + s0s[1] + s0s[2] + s0s[3] + s0s[4];
    float pr  = (s0 / (float)NPTS) / fmaxf(tot / (float)NPTS, 1e-12f);
    if (write_params && lane == 0) op[bk] = pr;

    // next-iteration coefs in-register
    float ic = 1.f / (var + 1e-6f);
    if (lane < FF) {
        float* R = ws + WS_R + (b * FF + lane) * 10;
        R[w]     = ic * m;
        R[5 + w] = -0.5f * ic;
    }
    float t1 = (lane < FF) ? logf(6.283185307179586f * var) : 0.f;
    float t2 = (lane < FF) ? ic * m * m : 0.f;
#pragma unroll
    for (int off = 1; off < 64; off <<= 1) {
        t1 += __shfl_xor(t1, off);
        t2 += __shfl_xor(t2, off);
    }
    if (lane == 0)
        (ws + WS_A)[bk] = logf(pr) - 0.5f * t1 - 0.5f * t2;
}

extern "C" void kernel_launch(void* const* d_in, const int* in_sizes, int n_in,
                              void* d_out, int out_size, void* d_ws, size_t ws_size,
                              hipStream_t stream) {
    const float* data     = (const float*)d_in[0];
    const float* in_means = (const float*)d_in[1];
    const float* in_var   = (const float*)d_in[2];
    const float* in_pi    = (const float*)d_in[3];
    float* ws  = (float*)d_ws;
    float* out = (float*)d_out;

    float* out_ll   = out;
    float* out_post = out + (size_t)BB * NPTS * KK;
    float* om       = out + 2 * (size_t)BB * NPTS * KK;
    float* ov       = om + BB * KK * FF;
    float* op       = ov + BB * KK * FF;

    // partials (8*5*125*8*44*4 = 7.04 MB) live in the ll output region (12.8 MB);
    // the final E-step fully overwrites it.
    float* partials = out_ll;

    prepare_kernel<<<1, 64, 0, stream>>>(in_means, in_var, in_pi, ws);

    for (int it = 0; it < 5; ++it) {
        estep_acc_kernel<<<BB * GG, 128, 0, stream>>>(data, ws, partials);
        update_kernel<<<BB, 320, 0, stream>>>(partials, ws, om, ov, op,
                                              (it == 4) ? 1 : 0);
    }
    estep_write_kernel<<<BB * GG, 128, 0, stream>>>(data, ws, out_ll, out_post);
}